// Round 11
// baseline (535.302 us; speedup 1.0000x reference)
//
#include <hip/hip_runtime.h>
#include <hip/hip_bf16.h>
#include <hip/hip_fp16.h>

#define T_TOKENS 4096
#define DIMC 1024
#define HID 4096
#define NE 8

typedef _Float16 f16;
typedef _Float16 f16x8 __attribute__((ext_vector_type(8)));
typedef _Float16 f16x4 __attribute__((ext_vector_type(4)));
typedef float f32x4 __attribute__((ext_vector_type(4)));

__device__ __forceinline__ void gload_lds16(const f16* g, f16* l) {
    __builtin_amdgcn_global_load_lds(
        (const __attribute__((address_space(1))) void*)g,
        (__attribute__((address_space(3))) void*)l, 16, 0, 0);
}

// ---------------------------------------------------------------------------
// Gating (fp32 exact) + bucket scatter. One wave per token.  [proven r3..r10]
// ---------------------------------------------------------------------------
__global__ __launch_bounds__(256) void gating_kernel(
    const float* __restrict__ x, const float* __restrict__ gw,
    const float* __restrict__ gb, int* __restrict__ counts,
    int* __restrict__ list)
{
    const int wave = threadIdx.x >> 6;
    const int lane = threadIdx.x & 63;
    const int t = blockIdx.x * 4 + wave;

    const float* xr = x + (size_t)t * DIMC;
    float acc[NE];
#pragma unroll
    for (int e = 0; e < NE; ++e) acc[e] = 0.f;

    for (int i = 0; i < DIMC / 64; ++i) {
        const int k = i * 64 + lane;
        const float xv = xr[k];
        const float* g = gw + (size_t)k * NE;
#pragma unroll
        for (int e = 0; e < NE; ++e) acc[e] = fmaf(xv, g[e], acc[e]);
    }
#pragma unroll
    for (int off = 32; off >= 1; off >>= 1) {
#pragma unroll
        for (int e = 0; e < NE; ++e) acc[e] += __shfl_xor(acc[e], off, 64);
    }
    if (lane == 0) {
        float lg[NE];
#pragma unroll
        for (int e = 0; e < NE; ++e) lg[e] = acc[e] + gb[e];
        int i1 = 0; float v1 = lg[0];
#pragma unroll
        for (int e = 1; e < NE; ++e) { if (lg[e] > v1) { v1 = lg[e]; i1 = e; } }
        int i2 = -1; float v2 = -3.4e38f;
#pragma unroll
        for (int e = 0; e < NE; ++e) {
            if (e == i1) continue;
            if (lg[e] > v2) { v2 = lg[e]; i2 = e; }
        }
        const int es = (i1 > i2) ? i1 : i2;
        const int pos = atomicAdd(&counts[es], 1);
        list[es * T_TOKENS + pos] = t;
    }
}

// ---------------------------------------------------------------------------
// x fp32 -> f16.  [proven r8]
// ---------------------------------------------------------------------------
__global__ __launch_bounds__(256) void xconvert(const float* __restrict__ x,
                                                f16* __restrict__ xh)
{
    const size_t i = ((size_t)blockIdx.x * 256 + threadIdx.x) * 8;
    const float4 a = *(const float4*)(x + i);
    const float4 b = *(const float4*)(x + i + 4);
    f16x8 v;
    v[0] = (f16)a.x; v[1] = (f16)a.y; v[2] = (f16)a.z; v[3] = (f16)a.w;
    v[4] = (f16)b.x; v[5] = (f16)b.y; v[6] = (f16)b.z; v[7] = (f16)b.w;
    *(f16x8*)(xh + i) = v;
}

// ---------------------------------------------------------------------------
// W [e][K][N] fp32 -> Wt [e][N][K] f16.  [proven r5/r8]
// ---------------------------------------------------------------------------
__global__ __launch_bounds__(256) void wconvert(const float* __restrict__ W,
                                                f16* __restrict__ Wt,
                                                int K, int N)
{
    __shared__ f16 Lt[64 * 72];
    const int n0 = blockIdx.x * 64;
    const int k0 = blockIdx.y * 64;
    const float* Ws = W + (size_t)blockIdx.z * K * N;
    const int t = threadIdx.x;

    const int no = (t & 15) * 4;
    const int kr = t >> 4;
#pragma unroll
    for (int p = 0; p < 4; ++p) {
        const int k = kr + p * 16;
        const float4 v = *(const float4*)(Ws + (size_t)(k0 + k) * N + n0 + no);
        Lt[(no + 0) * 72 + k] = (f16)v.x;
        Lt[(no + 1) * 72 + k] = (f16)v.y;
        Lt[(no + 2) * 72 + k] = (f16)v.z;
        Lt[(no + 3) * 72 + k] = (f16)v.w;
    }
    __syncthreads();
    const int n = t >> 2;
    const int ko = (t & 3) * 16;
    const f16x8 a = *(const f16x8*)&Lt[n * 72 + ko];
    const f16x8 b = *(const f16x8*)&Lt[n * 72 + ko + 8];
    f16* dst = Wt + ((size_t)blockIdx.z * N + n0 + n) * K + k0 + ko;
    *(f16x8*)(dst) = a;
    *(f16x8*)(dst + 8) = b;
}

// ---------------------------------------------------------------------------
// Grouped GEMM, 256x256 tile, 512 thr (8 waves 2m x 4n, per-wave 128x64),
// XCD-chunked swizzle (one expert per XCD; n fastest -> A and B re-reads
// served by XCD-local L2), 2-buffer counted-vmcnt pipeline (vmcnt(8)).
// Fragment/swizzle algebra identical to proven r8/r10 kernels.
// FIRST:  H = gelu(xh @ w1t + b1).   grid 2048: oid -> m=oid>>4, n=oid&15
// !FIRST: p[ks] = 2*acc (+2*b2 @ks==0), split-K=4. oid -> m=oid>>4,
//         ks=(oid>>2)&3, n=oid&3.  Non-atomic partials, reduce4 after.
// ---------------------------------------------------------------------------
template <bool FIRST>
__global__ __launch_bounds__(512) void ffn_gemm6(
    const f16* __restrict__ A, const f16* __restrict__ Bt,
    const float* __restrict__ bias, const int* __restrict__ counts,
    const int* __restrict__ list, f16* __restrict__ Hout,
    float* __restrict__ pout)
{
    constexpr int KB   = FIRST ? DIMC : HID;
    constexpr int NTOT = FIRST ? HID : DIMC;

    // XCD-chunked bijective swizzle: XCD g (= bid&7, assumed RR) owns
    // orig ids [g*256,(g+1)*256) = expert g's full tile set, n fastest.
    const int bid  = blockIdx.x;                  // 0..2047
    const int orig = (bid & 7) * 256 + (bid >> 3);
    const int e    = orig >> 8;
    const int oid  = orig & 255;
    const int m_t  = oid >> 4;
    const int n_t  = FIRST ? (oid & 15) : (oid & 3);
    const int ks   = FIRST ? 0 : ((oid >> 2) & 3);
    const int kk0  = ks * 1024;
    const int m0   = m_t * 256;
    const int n0   = n_t * 256;
    const int cnt  = counts[e];
    if (m0 >= cnt) return;

    __shared__ __align__(16) f16 As[2][256 * 64];   // 2 x 32 KB
    __shared__ __align__(16) f16 Bs[2][256 * 64];   // 2 x 32 KB
    __shared__ int rows[256];

    const int tid = threadIdx.x;
    if (tid < 256) rows[tid] = (m0 + tid < cnt) ? list[e * T_TOKENS + m0 + tid] : -1;
    __syncthreads();

    const int lane = tid & 63;
    const int wv   = tid >> 6;      // 0..7
    const int wr   = wv >> 2;       // 0..1  (128-row band)
    const int wc   = wv & 3;        // 0..3  (64-col band)

    // staging [proven r8 algebra]: wave wv covers rows wv*32+j*8+(lane>>3);
    // HW lane placement = base + lane*16B; source chunk = (lane&7)^(row&7).
    const f16* asrc[4];
    const f16* bsrc[4];
#pragma unroll
    for (int j = 0; j < 4; ++j) {
        const int row   = wv * 32 + j * 8 + (lane >> 3);
        const int chunk = (lane & 7) ^ (row & 7);
        int tok = rows[row]; if (tok < 0) tok = 0;   // junk, epilogue skips
        asrc[j] = A + (size_t)tok * KB + kk0 + chunk * 8;
        bsrc[j] = Bt + ((size_t)e * NTOT + n0 + row) * KB + kk0 + chunk * 8;
    }

    f32x4 acc[8][4];
#pragma unroll
    for (int mi = 0; mi < 8; ++mi)
#pragma unroll
        for (int ni = 0; ni < 4; ++ni) acc[mi][ni] = f32x4{0.f, 0.f, 0.f, 0.f};

#define STG(BUF, KT)                                                          \
    do {                                                                      \
        _Pragma("unroll")                                                     \
        for (int j = 0; j < 4; ++j) {                                         \
            gload_lds16(asrc[j] + (KT) * 64, &As[BUF][(wv * 32 + j * 8) * 64]); \
            gload_lds16(bsrc[j] + (KT) * 64, &Bs[BUF][(wv * 32 + j * 8) * 64]); \
        }                                                                     \
    } while (0)

#define CMP(BUF)                                                              \
    do {                                                                      \
        _Pragma("unroll")                                                     \
        for (int kh = 0; kh < 2; ++kh) {                                      \
            f16x8 af[8], bf[4];                                               \
            _Pragma("unroll")                                                 \
            for (int mi = 0; mi < 8; ++mi) {                                  \
                const int row = wr * 128 + mi * 16 + (lane & 15);             \
                const int kb  = (((lane >> 4) * 16) + kh * 64) ^ ((row & 7) << 4); \
                af[mi] = *(const f16x8*)((const char*)As[BUF] + row * 128 + kb);   \
            }                                                                 \
            _Pragma("unroll")                                                 \
            for (int ni = 0; ni < 4; ++ni) {                                  \
                const int n  = wc * 64 + ni * 16 + (lane & 15);               \
                const int kb = (((lane >> 4) * 16) + kh * 64) ^ ((n & 7) << 4);    \
                bf[ni] = *(const f16x8*)((const char*)Bs[BUF] + n * 128 + kb);     \
            }                                                                 \
            _Pragma("unroll")                                                 \
            for (int mi = 0; mi < 8; ++mi)                                    \
                _Pragma("unroll")                                             \
                for (int ni = 0; ni < 4; ++ni)                                \
                    acc[mi][ni] = __builtin_amdgcn_mfma_f32_16x16x32_f16(     \
                        af[mi], bf[ni], acc[mi][ni], 0, 0, 0);                \
        }                                                                     \
    } while (0)

    STG(0, 0);
#pragma unroll
    for (int k = 0; k < 8; ++k) {
        STG(1, 2 * k + 1);
        asm volatile("s_waitcnt vmcnt(8)" ::: "memory");   // stage 2k landed
        __builtin_amdgcn_s_barrier();
        __builtin_amdgcn_sched_barrier(0);
        CMP(0);
        __builtin_amdgcn_s_barrier();
        __builtin_amdgcn_sched_barrier(0);
        if (k < 7) {
            STG(0, 2 * k + 2);
            asm volatile("s_waitcnt vmcnt(8)" ::: "memory"); // stage 2k+1 landed
        } else {
            asm volatile("s_waitcnt vmcnt(0)" ::: "memory");
        }
        __builtin_amdgcn_s_barrier();
        __builtin_amdgcn_sched_barrier(0);
        CMP(1);
        __builtin_amdgcn_s_barrier();
        __builtin_amdgcn_sched_barrier(0);
    }
#undef STG
#undef CMP

    // ---- epilogue (proven mapping) ----
#pragma unroll
    for (int ni = 0; ni < 4; ++ni) {
        const int gc = n0 + wc * 64 + ni * 16 + (lane & 15);
        const float bv = FIRST ? bias[(size_t)e * HID + gc]
                               : ((ks == 0) ? 2.f * bias[(size_t)e * DIMC + gc] : 0.f);
#pragma unroll
        for (int mi = 0; mi < 8; ++mi) {
#pragma unroll
            for (int r = 0; r < 4; ++r) {
                const int lrow = wr * 128 + mi * 16 + (lane >> 4) * 4 + r;
                const int tok = rows[lrow];
                if (tok < 0) continue;
                if (FIRST) {
                    const float v = acc[mi][ni][r] + bv;
                    const float g = 0.5f * v * (1.f + erff(v * 0.70710678118f));
                    Hout[(size_t)tok * HID + gc] = (f16)g;
                } else {
                    pout[((size_t)ks * T_TOKENS + tok) * DIMC + gc] =
                        2.f * acc[mi][ni][r] + bv;
                }
            }
        }
    }
}

// ---------------------------------------------------------------------------
// out = p0 + p1 + p2 + p3   [proven r9]
// ---------------------------------------------------------------------------
__global__ __launch_bounds__(256) void reduce4(const float* __restrict__ p,
                                               float* __restrict__ out)
{
    constexpr size_t SL = (size_t)T_TOKENS * DIMC;
    const size_t i = ((size_t)blockIdx.x * 256 + threadIdx.x) * 4;
    const float4 a = *(const float4*)(p + i);
    const float4 b = *(const float4*)(p + SL + i);
    const float4 c = *(const float4*)(p + 2 * SL + i);
    const float4 d = *(const float4*)(p + 3 * SL + i);
    float4 s;
    s.x = a.x + b.x + c.x + d.x;
    s.y = a.y + b.y + c.y + d.y;
    s.z = a.z + b.z + c.z + d.z;
    s.w = a.w + b.w + c.w + d.w;
    *(float4*)(out + i) = s;
}

// ===========================================================================
// MID PATH (round-8, proven): 128^2 single-buffer + atomic split-K.
// Used when ws_size in [169MB, 233MB).
// ===========================================================================
template <bool FIRST>
__global__ __launch_bounds__(256) void ffn_gemm3(
    const f16* __restrict__ A, const f16* __restrict__ Bt,
    const float* __restrict__ bias, const int* __restrict__ counts,
    const int* __restrict__ list, f16* __restrict__ Hout,
    float* __restrict__ out)
{
    constexpr int KB   = FIRST ? DIMC : HID;
    constexpr int NTOT = FIRST ? HID : DIMC;
    constexpr int NKT  = 16;

    const int e   = FIRST ? (int)blockIdx.z : (int)(blockIdx.z >> 2);
    const int ks  = FIRST ? 0 : (int)(blockIdx.z & 3);
    const int kk0 = ks * 1024;
    const int m0  = blockIdx.y * 128;
    const int n0  = blockIdx.x * 128;
    const int cnt = counts[e];
    if (m0 >= cnt) return;

    __shared__ __align__(16) f16 As[128 * 64];
    __shared__ __align__(16) f16 Bs[128 * 64];
    __shared__ int rows[128];

    const int tid = threadIdx.x;
    if (tid < 128) rows[tid] = (m0 + tid < cnt) ? list[e * T_TOKENS + m0 + tid] : -1;
    __syncthreads();

    const int lane = tid & 63;
    const int wv   = tid >> 6;
    const int wr   = wv >> 1, wc = wv & 1;

    const f16* asrc[4];
    const f16* bsrc[4];
    f16* adst[4];
    f16* bdst[4];
#pragma unroll
    for (int j = 0; j < 4; ++j) {
        const int row   = wv * 32 + j * 8 + (lane >> 3);
        const int chunk = (lane & 7) ^ (row & 7);
        int tok = rows[row]; if (tok < 0) tok = 0;
        asrc[j] = A + (size_t)tok * KB + kk0 + chunk * 8;
        bsrc[j] = Bt + ((size_t)e * NTOT + n0 + row) * KB + kk0 + chunk * 8;
        adst[j] = As + (wv * 32 + j * 8) * 64;
        bdst[j] = Bs + (wv * 32 + j * 8) * 64;
    }

    f32x4 acc[4][4];
#pragma unroll
    for (int mi = 0; mi < 4; ++mi)
#pragma unroll
        for (int ni = 0; ni < 4; ++ni) acc[mi][ni] = f32x4{0.f, 0.f, 0.f, 0.f};

    for (int kt = 0; kt < NKT; ++kt) {
        const int ko = kt * 64;
        __syncthreads();
#pragma unroll
        for (int j = 0; j < 4; ++j) {
            gload_lds16(asrc[j] + ko, adst[j]);
            gload_lds16(bsrc[j] + ko, bdst[j]);
        }
        __syncthreads();
#pragma unroll
        for (int kh = 0; kh < 2; ++kh) {
            f16x8 af[4], bf[4];
#pragma unroll
            for (int mi = 0; mi < 4; ++mi) {
                const int row = wr * 64 + mi * 16 + (lane & 15);
                const int kb  = (((lane >> 4) * 16) + kh * 64) ^ ((row & 7) << 4);
                af[mi] = *(const f16x8*)((const char*)As + row * 128 + kb);
            }
#pragma unroll
            for (int ni = 0; ni < 4; ++ni) {
                const int n  = wc * 64 + ni * 16 + (lane & 15);
                const int kb = (((lane >> 4) * 16) + kh * 64) ^ ((n & 7) << 4);
                bf[ni] = *(const f16x8*)((const char*)Bs + n * 128 + kb);
            }
#pragma unroll
            for (int mi = 0; mi < 4; ++mi)
#pragma unroll
                for (int ni = 0; ni < 4; ++ni)
                    acc[mi][ni] = __builtin_amdgcn_mfma_f32_16x16x32_f16(
                        af[mi], bf[ni], acc[mi][ni], 0, 0, 0);
        }
    }

#pragma unroll
    for (int ni = 0; ni < 4; ++ni) {
        const int gc = n0 + wc * 64 + ni * 16 + (lane & 15);
        const float bv = FIRST ? bias[(size_t)e * HID + gc]
                               : ((ks == 0) ? 2.f * bias[(size_t)e * DIMC + gc] : 0.f);
#pragma unroll
        for (int mi = 0; mi < 4; ++mi) {
#pragma unroll
            for (int r = 0; r < 4; ++r) {
                const int lrow = wr * 64 + mi * 16 + (lane >> 4) * 4 + r;
                const int tok = rows[lrow];
                if (tok < 0) continue;
                if (FIRST) {
                    const float v = acc[mi][ni][r] + bv;
                    const float g = 0.5f * v * (1.f + erff(v * 0.70710678118f));
                    Hout[(size_t)tok * HID + gc] = (f16)g;
                } else {
                    atomicAdd(out + (size_t)tok * DIMC + gc,
                              2.f * acc[mi][ni][r] + bv);
                }
            }
        }
    }
}

// ---------------------------------------------------------------------------
extern "C" void kernel_launch(void* const* d_in, const int* in_sizes, int n_in,
                              void* d_out, int out_size, void* d_ws, size_t ws_size,
                              hipStream_t stream)
{
    const float* x   = (const float*)d_in[0];
    const float* gw  = (const float*)d_in[1];
    const float* gb  = (const float*)d_in[2];
    const float* w1  = (const float*)d_in[3];
    const float* b1  = (const float*)d_in[4];
    const float* w2  = (const float*)d_in[5];
    const float* b2  = (const float*)d_in[6];
    float* out = (float*)d_out;

    const size_t MB = 1 << 20;
    // layout: counts@0, list@1KB, xh@1MB(8MB), H@9MB(32MB),
    //         w1t@41MB(64MB), w2t@105MB(64MB), p@169MB(64MB) -> 233MB
    const size_t need_p   = 233 * MB;
    const size_t need_big = 169 * MB;
    if (ws_size < need_big) return;   // harness provides >=233MB (r9/r10 ran)

    int* counts = (int*)d_ws;
    int* list   = (int*)((char*)d_ws + 1024);
    f16* xh     = (f16*)((char*)d_ws + 1 * MB);
    f16* H      = (f16*)((char*)d_ws + 9 * MB);
    f16* w1t    = (f16*)((char*)d_ws + 41 * MB);
    f16* w2t    = (f16*)((char*)d_ws + 105 * MB);
    float* p    = (float*)((char*)d_ws + 169 * MB);

    hipMemsetAsync(counts, 0, 1024, stream);

    gating_kernel<<<T_TOKENS / 4, 256, 0, stream>>>(x, gw, gb, counts, list);
    xconvert<<<(T_TOKENS * DIMC) / (256 * 8), 256, 0, stream>>>(x, xh);
    wconvert<<<dim3(HID / 64, DIMC / 64, NE), 256, 0, stream>>>(w1, w1t, DIMC, HID);
    wconvert<<<dim3(DIMC / 64, HID / 64, NE), 256, 0, stream>>>(w2, w2t, HID, DIMC);

    if (ws_size >= need_p) {
        // fast path: 256^2 tiles, XCD-chunked swizzle, counted-vmcnt 2-buffer
        ffn_gemm6<true><<<2048, 512, 0, stream>>>(
            xh, w1t, b1, counts, list, H, nullptr);
        ffn_gemm6<false><<<2048, 512, 0, stream>>>(
            H, w2t, b2, counts, list, nullptr, p);
        reduce4<<<(T_TOKENS * DIMC) / (256 * 4), 256, 0, stream>>>(p, out);
    } else {
        // mid path (round-8 proven): single-buffer + atomics
        hipMemsetAsync(out, 0, (size_t)T_TOKENS * DIMC * sizeof(float), stream);
        ffn_gemm3<true><<<dim3(HID / 128, T_TOKENS / 128, NE), 256, 0, stream>>>(
            xh, w1t, b1, counts, list, H, nullptr);
        ffn_gemm3<false><<<dim3(DIMC / 128, T_TOKENS / 128, NE * 4), 256, 0, stream>>>(
            H, w2t, b2, counts, list, nullptr, out);
    }
}

// Round 12
// 341.584 us; speedup vs baseline: 1.5671x; 1.5671x over previous
//
#include <hip/hip_runtime.h>
#include <hip/hip_bf16.h>
#include <hip/hip_fp16.h>

#define T_TOKENS 4096
#define DIMC 1024
#define HID 4096
#define NE 8

typedef _Float16 f16;
typedef _Float16 f16x8 __attribute__((ext_vector_type(8)));
typedef _Float16 f16x4 __attribute__((ext_vector_type(4)));
typedef float f32x4 __attribute__((ext_vector_type(4)));

__device__ __forceinline__ void gload_lds16(const f16* g, f16* l) {
    __builtin_amdgcn_global_load_lds(
        (const __attribute__((address_space(1))) void*)g,
        (__attribute__((address_space(3))) void*)l, 16, 0, 0);
}

// ---------------------------------------------------------------------------
// Gating (fp32 exact) + bucket scatter + token->expert map.  [proven r3..r11,
// + eidx store]
// ---------------------------------------------------------------------------
__global__ __launch_bounds__(256) void gating_kernel(
    const float* __restrict__ x, const float* __restrict__ gw,
    const float* __restrict__ gb, int* __restrict__ counts,
    int* __restrict__ list, int* __restrict__ eidx)
{
    const int wave = threadIdx.x >> 6;
    const int lane = threadIdx.x & 63;
    const int t = blockIdx.x * 4 + wave;

    const float* xr = x + (size_t)t * DIMC;
    float acc[NE];
#pragma unroll
    for (int e = 0; e < NE; ++e) acc[e] = 0.f;

    for (int i = 0; i < DIMC / 64; ++i) {
        const int k = i * 64 + lane;
        const float xv = xr[k];
        const float* g = gw + (size_t)k * NE;
#pragma unroll
        for (int e = 0; e < NE; ++e) acc[e] = fmaf(xv, g[e], acc[e]);
    }
#pragma unroll
    for (int off = 32; off >= 1; off >>= 1) {
#pragma unroll
        for (int e = 0; e < NE; ++e) acc[e] += __shfl_xor(acc[e], off, 64);
    }
    if (lane == 0) {
        float lg[NE];
#pragma unroll
        for (int e = 0; e < NE; ++e) lg[e] = acc[e] + gb[e];
        int i1 = 0; float v1 = lg[0];
#pragma unroll
        for (int e = 1; e < NE; ++e) { if (lg[e] > v1) { v1 = lg[e]; i1 = e; } }
        int i2 = -1; float v2 = -3.4e38f;
#pragma unroll
        for (int e = 0; e < NE; ++e) {
            if (e == i1) continue;
            if (lg[e] > v2) { v2 = lg[e]; i2 = e; }
        }
        const int es = (i1 > i2) ? i1 : i2;
        const int pos = atomicAdd(&counts[es], 1);
        list[es * T_TOKENS + pos] = t;
        eidx[t] = es;
    }
}

// ---------------------------------------------------------------------------
// x fp32 -> f16.  [proven r8]
// ---------------------------------------------------------------------------
__global__ __launch_bounds__(256) void xconvert(const float* __restrict__ x,
                                                f16* __restrict__ xh)
{
    const size_t i = ((size_t)blockIdx.x * 256 + threadIdx.x) * 8;
    const float4 a = *(const float4*)(x + i);
    const float4 b = *(const float4*)(x + i + 4);
    f16x8 v;
    v[0] = (f16)a.x; v[1] = (f16)a.y; v[2] = (f16)a.z; v[3] = (f16)a.w;
    v[4] = (f16)b.x; v[5] = (f16)b.y; v[6] = (f16)b.z; v[7] = (f16)b.w;
    *(f16x8*)(xh + i) = v;
}

// ---------------------------------------------------------------------------
// W [e][K][N] fp32 -> Wt [e][N][K] f16.  [proven r5/r8]
// ---------------------------------------------------------------------------
__global__ __launch_bounds__(256) void wconvert(const float* __restrict__ W,
                                                f16* __restrict__ Wt,
                                                int K, int N)
{
    __shared__ f16 Lt[64 * 72];
    const int n0 = blockIdx.x * 64;
    const int k0 = blockIdx.y * 64;
    const float* Ws = W + (size_t)blockIdx.z * K * N;
    const int t = threadIdx.x;

    const int no = (t & 15) * 4;
    const int kr = t >> 4;
#pragma unroll
    for (int p = 0; p < 4; ++p) {
        const int k = kr + p * 16;
        const float4 v = *(const float4*)(Ws + (size_t)(k0 + k) * N + n0 + no);
        Lt[(no + 0) * 72 + k] = (f16)v.x;
        Lt[(no + 1) * 72 + k] = (f16)v.y;
        Lt[(no + 2) * 72 + k] = (f16)v.z;
        Lt[(no + 3) * 72 + k] = (f16)v.w;
    }
    __syncthreads();
    const int n = t >> 2;
    const int ko = (t & 3) * 16;
    const f16x8 a = *(const f16x8*)&Lt[n * 72 + ko];
    const f16x8 b = *(const f16x8*)&Lt[n * 72 + ko + 8];
    f16* dst = Wt + ((size_t)blockIdx.z * N + n0 + n) * K + k0 + ko;
    *(f16x8*)(dst) = a;
    *(f16x8*)(dst + 8) = b;
}

// ---------------------------------------------------------------------------
// Grouped GEMM, r8-proven core (128x128, BK=64, single-buffer, 2 barriers,
// global_load_lds + involution swizzle).  Split-K both stages:
// FIRST:  split-K=2 (z: e=z>>1, ks=z&1, 8 K-iters).  Epilogue = bare f16
//         store of acc into Hp[ks][tok][gc]  (bias+gelu deferred).
// !FIRST: split-K=4 (z: e=z>>2, ks=z&3, 16 K-iters).  Epilogue = fp32
//         partial 2*acc (+2*b2 @ks==0) into p[ks]; reduce4 sums.
// ---------------------------------------------------------------------------
template <bool FIRST>
__global__ __launch_bounds__(256) void ffn_gemm7(
    const f16* __restrict__ A, const f16* __restrict__ Bt,
    const float* __restrict__ bias, const int* __restrict__ counts,
    const int* __restrict__ list, f16* __restrict__ Hp,
    float* __restrict__ pout)
{
    constexpr int KB   = FIRST ? DIMC : HID;
    constexpr int NTOT = FIRST ? HID : DIMC;
    constexpr int NKT  = FIRST ? 8 : 16;      // K-iters per chunk
    constexpr int KCH  = FIRST ? 512 : 1024;  // chunk length

    const int zz  = blockIdx.z;
    const int e   = FIRST ? (zz >> 1) : (zz >> 2);
    const int ks  = FIRST ? (zz & 1) : (zz & 3);
    const int kk0 = ks * KCH;
    const int m0  = blockIdx.y * 128;
    const int n0  = blockIdx.x * 128;
    const int cnt = counts[e];
    if (m0 >= cnt) return;

    __shared__ __align__(16) f16 As[128 * 64];
    __shared__ __align__(16) f16 Bs[128 * 64];
    __shared__ int rows[128];

    const int tid = threadIdx.x;
    if (tid < 128) rows[tid] = (m0 + tid < cnt) ? list[e * T_TOKENS + m0 + tid] : -1;
    __syncthreads();

    const int lane = tid & 63;
    const int wv   = tid >> 6;
    const int wr   = wv >> 1, wc = wv & 1;

    // staging [proven r8]: wave wv covers rows wv*32+j*8+(lane>>3);
    // HW lane placement = base + lane*16B; source chunk = (lane&7)^(row&7).
    const f16* asrc[4];
    const f16* bsrc[4];
    f16* adst[4];
    f16* bdst[4];
#pragma unroll
    for (int j = 0; j < 4; ++j) {
        const int row   = wv * 32 + j * 8 + (lane >> 3);
        const int chunk = (lane & 7) ^ (row & 7);
        int tok = rows[row]; if (tok < 0) tok = 0;
        asrc[j] = A + (size_t)tok * KB + kk0 + chunk * 8;
        bsrc[j] = Bt + ((size_t)e * NTOT + n0 + row) * KB + kk0 + chunk * 8;
        adst[j] = As + (wv * 32 + j * 8) * 64;
        bdst[j] = Bs + (wv * 32 + j * 8) * 64;
    }

    f32x4 acc[4][4];
#pragma unroll
    for (int mi = 0; mi < 4; ++mi)
#pragma unroll
        for (int ni = 0; ni < 4; ++ni) acc[mi][ni] = f32x4{0.f, 0.f, 0.f, 0.f};

    for (int kt = 0; kt < NKT; ++kt) {
        const int ko = kt * 64;
        __syncthreads();
#pragma unroll
        for (int j = 0; j < 4; ++j) {
            gload_lds16(asrc[j] + ko, adst[j]);
            gload_lds16(bsrc[j] + ko, bdst[j]);
        }
        __syncthreads();
#pragma unroll
        for (int kh = 0; kh < 2; ++kh) {
            f16x8 af[4], bf[4];
#pragma unroll
            for (int mi = 0; mi < 4; ++mi) {
                const int row = wr * 64 + mi * 16 + (lane & 15);
                const int kb  = (((lane >> 4) * 16) + kh * 64) ^ ((row & 7) << 4);
                af[mi] = *(const f16x8*)((const char*)As + row * 128 + kb);
            }
#pragma unroll
            for (int ni = 0; ni < 4; ++ni) {
                const int n  = wc * 64 + ni * 16 + (lane & 15);
                const int kb = (((lane >> 4) * 16) + kh * 64) ^ ((n & 7) << 4);
                bf[ni] = *(const f16x8*)((const char*)Bs + n * 128 + kb);
            }
#pragma unroll
            for (int mi = 0; mi < 4; ++mi)
#pragma unroll
                for (int ni = 0; ni < 4; ++ni)
                    acc[mi][ni] = __builtin_amdgcn_mfma_f32_16x16x32_f16(
                        af[mi], bf[ni], acc[mi][ni], 0, 0, 0);
        }
    }

    // ---- epilogue (proven C/D mapping) ----
#pragma unroll
    for (int ni = 0; ni < 4; ++ni) {
        const int gc = n0 + wc * 64 + ni * 16 + (lane & 15);
        const float bv = FIRST ? 0.f
                               : ((ks == 0) ? 2.f * bias[(size_t)e * DIMC + gc] : 0.f);
#pragma unroll
        for (int mi = 0; mi < 4; ++mi) {
#pragma unroll
            for (int r = 0; r < 4; ++r) {
                const int lrow = wr * 64 + mi * 16 + (lane >> 4) * 4 + r;
                const int tok = rows[lrow];
                if (tok < 0) continue;
                if (FIRST) {
                    Hp[((size_t)ks * T_TOKENS + tok) * HID + gc] =
                        (f16)acc[mi][ni][r];           // bare store; gelu later
                } else {
                    pout[((size_t)ks * T_TOKENS + tok) * DIMC + gc] =
                        2.f * acc[mi][ni][r] + bv;
                }
            }
        }
    }
}

// ---------------------------------------------------------------------------
// H[t][c] = gelu(Hp0[t][c] + Hp1[t][c] + b1[eidx[t]][c])  -- memory-bound,
// erff cost hidden under ~100MB of traffic.  8 elems/thread.
// ---------------------------------------------------------------------------
__global__ __launch_bounds__(256) void gelu_combine(
    const f16* __restrict__ Hp, const float* __restrict__ b1,
    const int* __restrict__ eidx, f16* __restrict__ H)
{
    const size_t i = ((size_t)blockIdx.x * 256 + threadIdx.x) * 8;
    const int t = (int)(i >> 12);          // / HID
    const int c = (int)(i & (HID - 1));
    const int e = eidx[t];
    const f16x8 a = *(const f16x8*)(Hp + i);
    const f16x8 b = *(const f16x8*)(Hp + (size_t)T_TOKENS * HID + i);
    const float4 ba = *(const float4*)(b1 + (size_t)e * HID + c);
    const float4 bb = *(const float4*)(b1 + (size_t)e * HID + c + 4);
    const float bj[8] = {ba.x, ba.y, ba.z, ba.w, bb.x, bb.y, bb.z, bb.w};
    f16x8 o;
#pragma unroll
    for (int j = 0; j < 8; ++j) {
        const float v = (float)a[j] + (float)b[j] + bj[j];
        o[j] = (f16)(0.5f * v * (1.f + erff(v * 0.70710678118f)));
    }
    *(f16x8*)(H + i) = o;
}

// ---------------------------------------------------------------------------
// out = p0 + p1 + p2 + p3   [proven r9]
// ---------------------------------------------------------------------------
__global__ __launch_bounds__(256) void reduce4(const float* __restrict__ p,
                                               float* __restrict__ out)
{
    constexpr size_t SL = (size_t)T_TOKENS * DIMC;
    const size_t i = ((size_t)blockIdx.x * 256 + threadIdx.x) * 4;
    const float4 a = *(const float4*)(p + i);
    const float4 b = *(const float4*)(p + SL + i);
    const float4 c = *(const float4*)(p + 2 * SL + i);
    const float4 d = *(const float4*)(p + 3 * SL + i);
    float4 s;
    s.x = a.x + b.x + c.x + d.x;
    s.y = a.y + b.y + c.y + d.y;
    s.z = a.z + b.z + c.z + d.z;
    s.w = a.w + b.w + c.w + d.w;
    *(float4*)(out + i) = s;
}

// ===========================================================================
// FALLBACK (round-3, proven) — used when ws_size < 233MB.
// ===========================================================================
template <bool FIRST>
__global__ __launch_bounds__(256) void ffn_gemm_fb(
    const float* __restrict__ x, const f16* __restrict__ Hin,
    const float* __restrict__ w1, const float* __restrict__ b1,
    const float* __restrict__ w2, const float* __restrict__ b2,
    const int* __restrict__ counts, const int* __restrict__ list,
    f16* __restrict__ Hout, float* __restrict__ out)
{
    constexpr int K = FIRST ? DIMC : HID;
    constexpr int N = FIRST ? HID : DIMC;
    constexpr int LDT = 40;

    const int e  = blockIdx.z;
    const int m0 = blockIdx.y * 128;
    const int n0 = blockIdx.x * 128;
    const int cnt = counts[e];
    if (m0 >= cnt) return;

    __shared__ f16 Ab[128 * LDT];
    __shared__ f16 Bb[128 * LDT];
    __shared__ int rows[128];

    const int tid = threadIdx.x;
    if (tid < 128) {
        const int p = m0 + tid;
        rows[tid] = (p < cnt) ? list[e * T_TOKENS + p] : -1;
    }
    __syncthreads();

    const int lane = tid & 63;
    const int wv = tid >> 6;
    const int wr = wv >> 1, wc = wv & 1;

    f32x4 acc[4][4];
#pragma unroll
    for (int mi = 0; mi < 4; ++mi)
#pragma unroll
        for (int ni = 0; ni < 4; ++ni) acc[mi][ni] = f32x4{0.f, 0.f, 0.f, 0.f};

    const float* Bsrc = (FIRST ? w1 : w2) + (size_t)e * K * N;

    for (int kk = 0; kk < K; kk += 32) {
        __syncthreads();
        {
            const int r  = tid >> 3;
            const int ko = (tid & 7) * 4;
#pragma unroll
            for (int p = 0; p < 4; ++p) {
                const int row = p * 32 + r;
                const int tok = rows[row];
                f16x4 hv;
                if (FIRST) {
                    float4 v;
                    if (tok >= 0) v = *(const float4*)(x + (size_t)tok * K + kk + ko);
                    else          v = make_float4(0.f, 0.f, 0.f, 0.f);
                    hv[0] = (f16)v.x; hv[1] = (f16)v.y; hv[2] = (f16)v.z; hv[3] = (f16)v.w;
                } else {
                    if (tok >= 0) hv = *(const f16x4*)(Hin + (size_t)tok * K + kk + ko);
                    else { hv[0] = (f16)0.f; hv[1] = (f16)0.f; hv[2] = (f16)0.f; hv[3] = (f16)0.f; }
                }
                *(f16x4*)&Ab[row * LDT + ko] = hv;
            }
        }
        {
            const int kb = tid >> 5;
            const int no = (tid & 31) * 4;
#pragma unroll
            for (int p = 0; p < 4; ++p) {
                const int k = p * 8 + kb;
                const float4 v = *(const float4*)(Bsrc + (size_t)(kk + k) * N + n0 + no);
                f16 h[4];
                h[0] = (f16)v.x; h[1] = (f16)v.y; h[2] = (f16)v.z; h[3] = (f16)v.w;
#pragma unroll
                for (int i = 0; i < 4; ++i) {
                    const int n = no + i;
                    const int chunk = (k >> 3) ^ ((n >> 2) & 3);
                    Bb[n * LDT + chunk * 8 + (k & 7)] = h[i];
                }
            }
        }
        __syncthreads();
        f16x8 af[4], bf[4];
#pragma unroll
        for (int mi = 0; mi < 4; ++mi) {
            const int row = wr * 64 + mi * 16 + (lane & 15);
            af[mi] = *(const f16x8*)&Ab[row * LDT + (lane >> 4) * 8];
        }
#pragma unroll
        for (int ni = 0; ni < 4; ++ni) {
            const int n = wc * 64 + ni * 16 + (lane & 15);
            const int chunk = (lane >> 4) ^ ((n >> 2) & 3);
            bf[ni] = *(const f16x8*)&Bb[n * LDT + chunk * 8];
        }
#pragma unroll
        for (int mi = 0; mi < 4; ++mi)
#pragma unroll
            for (int ni = 0; ni < 4; ++ni)
                acc[mi][ni] = __builtin_amdgcn_mfma_f32_16x16x32_f16(
                    af[mi], bf[ni], acc[mi][ni], 0, 0, 0);
    }

#pragma unroll
    for (int ni = 0; ni < 4; ++ni) {
        const int gc = n0 + wc * 64 + ni * 16 + (lane & 15);
        const float bias = FIRST ? b1[(size_t)e * HID + gc]
                                 : b2[(size_t)e * DIMC + gc];
#pragma unroll
        for (int mi = 0; mi < 4; ++mi) {
#pragma unroll
            for (int r = 0; r < 4; ++r) {
                const int lrow = wr * 64 + mi * 16 + (lane >> 4) * 4 + r;
                const int tok = rows[lrow];
                if (tok < 0) continue;
                const float v = acc[mi][ni][r] + bias;
                if (FIRST) {
                    const float g = 0.5f * v * (1.f + erff(v * 0.70710678118f));
                    Hout[(size_t)tok * HID + gc] = (f16)g;
                } else {
                    out[(size_t)tok * DIMC + gc] = 2.f * v;
                }
            }
        }
    }
}

// ---------------------------------------------------------------------------
extern "C" void kernel_launch(void* const* d_in, const int* in_sizes, int n_in,
                              void* d_out, int out_size, void* d_ws, size_t ws_size,
                              hipStream_t stream)
{
    const float* x   = (const float*)d_in[0];
    const float* gw  = (const float*)d_in[1];
    const float* gb  = (const float*)d_in[2];
    const float* w1  = (const float*)d_in[3];
    const float* b1  = (const float*)d_in[4];
    const float* w2  = (const float*)d_in[5];
    const float* b2  = (const float*)d_in[6];
    float* out = (float*)d_out;

    const size_t MB = 1 << 20;
    // layout: counts@0(1KB), list@1KB(128KB), eidx@512KB(16KB),
    //         xh@1MB(8MB), H@9MB(32MB), w1t@41MB(64MB), w2t@105MB(64MB),
    //         p/Hp@169MB(64MB) -> 233MB   (Hp = f16[2][T][HID] reused as p)
    const size_t need_p = 233 * MB;

    if (ws_size >= need_p) {
        int* counts = (int*)d_ws;
        int* list   = (int*)((char*)d_ws + 1024);
        int* eidx   = (int*)((char*)d_ws + 512 * 1024);
        f16* xh     = (f16*)((char*)d_ws + 1 * MB);
        f16* H      = (f16*)((char*)d_ws + 9 * MB);
        f16* w1t    = (f16*)((char*)d_ws + 41 * MB);
        f16* w2t    = (f16*)((char*)d_ws + 105 * MB);
        f16* Hp     = (f16*)((char*)d_ws + 169 * MB);   // 64MB, then reused:
        float* p    = (float*)((char*)d_ws + 169 * MB); // fp32 partials GEMM2

        hipMemsetAsync(counts, 0, 1024, stream);

        gating_kernel<<<T_TOKENS / 4, 256, 0, stream>>>(x, gw, gb, counts, list, eidx);
        xconvert<<<(T_TOKENS * DIMC) / (256 * 8), 256, 0, stream>>>(x, xh);
        wconvert<<<dim3(HID / 64, DIMC / 64, NE), 256, 0, stream>>>(w1, w1t, DIMC, HID);
        wconvert<<<dim3(DIMC / 64, HID / 64, NE), 256, 0, stream>>>(w2, w2t, HID, DIMC);

        // GEMM1: split-K=2, bare f16 partials
        ffn_gemm7<true><<<dim3(HID / 128, T_TOKENS / 128, NE * 2), 256, 0, stream>>>(
            xh, w1t, nullptr, counts, list, Hp, nullptr);
        // combine: H = gelu(Hp0+Hp1+b1[e])
        gelu_combine<<<(T_TOKENS * HID) / (256 * 8), 256, 0, stream>>>(Hp, b1, eidx, H);
        // GEMM2: split-K=4, fp32 partials (overwrites Hp region)
        ffn_gemm7<false><<<dim3(DIMC / 128, T_TOKENS / 128, NE * 4), 256, 0, stream>>>(
            H, w2t, b2, counts, list, nullptr, p);
        reduce4<<<(T_TOKENS * DIMC) / (256 * 4), 256, 0, stream>>>(p, out);
        return;
    }

    // ---- fallback (round-3 path, needs 33MB) ----
    const size_t need_fb = (size_t)(1 << 18) + (size_t)T_TOKENS * HID * sizeof(f16);
    if (ws_size < need_fb) return;

    int* counts = (int*)d_ws;
    int* list   = (int*)((char*)d_ws + 1024);
    int* eidx   = (int*)((char*)d_ws + 160 * 1024);
    f16* H      = (f16*)((char*)d_ws + (1 << 18));

    hipMemsetAsync(d_ws, 0, 1024, stream);
    gating_kernel<<<T_TOKENS / 4, 256, 0, stream>>>(x, gw, gb, counts, list, eidx);
    ffn_gemm_fb<true><<<dim3(HID / 128, T_TOKENS / 128, NE), 256, 0, stream>>>(
        x, (const f16*)nullptr, w1, b1, w2, b2, counts, list, H, out);
    ffn_gemm_fb<false><<<dim3(DIMC / 128, T_TOKENS / 128, NE), 256, 0, stream>>>(
        x, (const f16*)H, w1, b1, w2, b2, counts, list, H, out);
}